// Round 9
// baseline (465.854 us; speedup 1.0000x reference)
//
#include <hip/hip_runtime.h>
#include <hip/hip_bf16.h>
#include <math.h>

typedef __attribute__((ext_vector_type(8))) short bf16x8;
typedef __attribute__((ext_vector_type(4))) float f32x4;

__device__ inline unsigned short f2bf(float f) {
    return __builtin_bit_cast(unsigned short, __float2bfloat16(f));
}
__device__ inline float bf2f(unsigned short u) {
    return __bfloat162float(__builtin_bit_cast(__hip_bfloat16, u));
}
__device__ inline bf16x8 cvt8(float4 a, float4 b) {
    bf16x8 r;
    r[0]=(short)f2bf(a.x); r[1]=(short)f2bf(a.y); r[2]=(short)f2bf(a.z); r[3]=(short)f2bf(a.w);
    r[4]=(short)f2bf(b.x); r[5]=(short)f2bf(b.y); r[6]=(short)f2bf(b.z); r[7]=(short)f2bf(b.w);
    return r;
}
__device__ inline void split8(float4 a, float4 b, bf16x8& hi, bf16x8& lo) {
    float f[8] = {a.x,a.y,a.z,a.w,b.x,b.y,b.z,b.w};
    #pragma unroll
    for (int i = 0; i < 8; ++i) {
        unsigned short h = f2bf(f[i]);
        hi[i] = (short)h;
        lo[i] = (short)f2bf(f[i] - bf2f(h));
    }
}

// LDS map (float-index units; total 9996 fl = 39984 B -> 4 blocks/CU):
//  xv   f32 [25][65]      @0     whole block (LN src, xv_bf src, residual)
//  ynh  u16 [25][64] swz  @1625  P1->P2  (frag spill-reads into ynl: garbage, discarded)
//  ynl  u16 [25][64] swz  @2425  P1->P2  (spill-reads into qkb: garbage, discarded)
//  res  f32 [64][25]      @1625  P5->store (overlays yn; disjoint from A_bf/U_T)
//  qkb  f32 [25][52]      @3225  P2->P3
//  A_bf u16 [80][36]      @3225  P4->P5  (overlays qkb; spill-reads into U_T head: discarded)
//  U_T  u16 [192][36]     @4665  P2->P5  (cols 0..31 used; stride-36 = conflict-free)
//  xvbf u16 [32][64] swz  @8121  P1->P2  (rows 25..31 zeroed)
//  Abuf f32 [75][25]      @8121  P3->P4  (overlays xvbf)
#define LDS_FLOATS 9996

__global__ __launch_bounds__(256, 4)
void agcn_fused_kernel(const float* __restrict__ x,
                       const float* __restrict__ PA,
                       const float* __restrict__ ln_g, const float* __restrict__ ln_b,
                       const float* __restrict__ Wqk, const float* __restrict__ bqk,
                       const float* __restrict__ conv_w, const float* __restrict__ conv_b,
                       const float* __restrict__ bn_g, const float* __restrict__ bn_b,
                       const float* __restrict__ bn_m, const float* __restrict__ bn_v,
                       float* __restrict__ out)
{
    __shared__ float lds[LDS_FLOATS];
    float* xv = lds;                                        // [25][65]
    unsigned short* ynh  = (unsigned short*)(lds + 1625);
    unsigned short* ynl  = (unsigned short*)(lds + 2425);
    float* res  = lds + 1625;                               // [64][25]
    float* qkb  = lds + 3225;                               // [25][52]
    unsigned short* A_bf = (unsigned short*)(lds + 3225);   // [80][36]
    unsigned short* U_T  = (unsigned short*)(lds + 4665);   // [192][36]
    unsigned short* xvbf = (unsigned short*)(lds + 8121);   // [32][64] swz
    float* Abuf = lds + 8121;                               // [75][25]

    const int bid = blockIdx.x;
    const int n = bid >> 7, t = bid & 127;
    const int tid = threadIdx.x;
    const int lane = tid & 63, w = tid >> 6;
    const int g = lane >> 4, l15 = lane & 15;
    const int o = 16 * w + l15;

    // ============ prologue: issue all param loads ============
    float4 cw_f[12];
    #pragma unroll
    for (int kt = 0; kt < 6; ++kt) {
        const float* wp = &conv_w[(kt >> 1) * 4096 + o * 64 + (kt & 1) * 32 + 8 * g];
        cw_f[2*kt]   = *(const float4*)wp;
        cw_f[2*kt+1] = *(const float4*)(wp + 4);
    }
    float4 wq_f[4];
    float bq = 0.f;
    if (w < 3) {
        const int j = 16 * w + l15;
        #pragma unroll
        for (int ks = 0; ks < 2; ++ks) {
            const float* wp = &Wqk[j * 64 + ks * 32 + 8 * g];
            wq_f[2*ks]   = *(const float4*)wp;
            wq_f[2*ks+1] = *(const float4*)(wp + 4);
        }
        bq = bqk[j];
    }
    const float lg = ln_g[lane], lb = ln_b[lane];
    const float sc_e = bn_g[o] * rsqrtf(bn_v[o] + 1e-5f);
    const float bi_e = (conv_b[o] + conv_b[64 + o] + conv_b[128 + o]) * sc_e
                       + bn_b[o] - bn_m[o] * sc_e;

    // stage x tile
    {
        const float* xb = x + (size_t)n * 204800 + t * 25;
        for (int idx = tid; idx < 1600; idx += 256) {
            int c = idx / 25, v = idx - c * 25;
            xv[v * 65 + c] = xb[c * 3200 + v];
        }
    }

    bf16x8 cw[6];
    #pragma unroll
    for (int kt = 0; kt < 6; ++kt) cw[kt] = cvt8(cw_f[2*kt], cw_f[2*kt+1]);
    bf16x8 wqh[2], wql[2];
    if (w < 3) {
        #pragma unroll
        for (int ks = 0; ks < 2; ++ks) split8(wq_f[2*ks], wq_f[2*ks+1], wqh[ks], wql[ks]);
    }
    __syncthreads();

    // ---- P1: LayerNorm (one-pass, interleaved reduces) + xvbf build ----
    for (int v = w; v < 25; v += 4) {
        float val = xv[v * 65 + lane];
        float s1 = val, s2 = val * val;
        for (int off = 32; off; off >>= 1) {
            s1 += __shfl_xor(s1, off);
            s2 += __shfl_xor(s2, off);
        }
        float mu = s1 * (1.0f / 64.0f);
        float var = s2 * (1.0f / 64.0f) - mu * mu;
        float rstd = rsqrtf(var + 1e-5f);
        float y = (val - mu) * rstd * lg + lb;
        unsigned short hh = f2bf(y);
        unsigned short ll = f2bf(y - bf2f(hh));
        int idx = (v * 64 + lane) ^ ((v & 7) << 3);
        ynh[idx] = hh;
        ynl[idx] = ll;
    }
    // xvbf[v][c] bf16, rows 25..31 zeroed, c-bits 3..5 XOR'd by (v&7)
    {
        int v = tid >> 3, c0 = (tid & 7) * 8;
        bf16x8 pack;
        #pragma unroll
        for (int i = 0; i < 8; ++i)
            pack[i] = (v < 25) ? (short)f2bf(xv[v * 65 + c0 + i]) : (short)0;
        int base = v * 64 + (c0 ^ ((v & 7) << 3));
        *(bf16x8*)&xvbf[base] = pack;
    }
    __syncthreads();

    // ---- P2: qk MFMA (waves 0-2) -> qkb ; U MFMA (all waves) -> U_T ----
    if (w < 3) {
        const int j = 16 * w + l15;
        #pragma unroll
        for (int mt = 0; mt < 2; ++mt) {
            f32x4 acc = {bq, bq, bq, bq};
            #pragma unroll
            for (int ks = 0; ks < 2; ++ks) {
                int row = 16 * mt + l15;
                int idx = (row * 64 + ks * 32 + 8 * g) ^ ((row & 7) << 3);
                bf16x8 ah = *(bf16x8*)&ynh[idx];
                bf16x8 al = *(bf16x8*)&ynl[idx];
                acc = __builtin_amdgcn_mfma_f32_16x16x32_bf16(al, wqh[ks], acc, 0, 0, 0);
                acc = __builtin_amdgcn_mfma_f32_16x16x32_bf16(ah, wql[ks], acc, 0, 0, 0);
                acc = __builtin_amdgcn_mfma_f32_16x16x32_bf16(ah, wqh[ks], acc, 0, 0, 0);
            }
            #pragma unroll
            for (int reg = 0; reg < 4; ++reg) {
                int v = 16 * mt + 4 * g + reg;
                if (v < 25) qkb[v * 52 + j] = acc[reg];
            }
        }
    }
    // U_h = xv . W_h^T : A-frag = cw (m-row = o), B-frag = xvbf (n = j, k = c)
    {
        bf16x8 bU[2][2];
        #pragma unroll
        for (int nt = 0; nt < 2; ++nt)
            #pragma unroll
            for (int ks = 0; ks < 2; ++ks) {
                int idx = (16 * nt + l15) * 64 + ((32 * ks + 8 * g) ^ ((l15 & 7) << 3));
                bU[nt][ks] = *(bf16x8*)&xvbf[idx];
            }
        #pragma unroll
        for (int h = 0; h < 3; ++h)
            #pragma unroll
            for (int nt = 0; nt < 2; ++nt) {
                f32x4 au = {0.f, 0.f, 0.f, 0.f};
                au = __builtin_amdgcn_mfma_f32_16x16x32_bf16(cw[2*h+0], bU[nt][0], au, 0, 0, 0);
                au = __builtin_amdgcn_mfma_f32_16x16x32_bf16(cw[2*h+1], bU[nt][1], au, 0, 0, 0);
                #pragma unroll
                for (int reg = 0; reg < 4; ++reg) {
                    int row = h * 64 + 16 * w + 4 * g + reg;
                    U_T[row * 36 + 16 * nt + l15] = f2bf(au[reg]);
                }
            }
    }
    __syncthreads();

    // ---- P3: dots (fp32 VALU) -> Abuf ----
    for (int idx = tid; idx < 1875; idx += 256) {
        int h = idx / 625, r = idx - h * 625;
        int i = r / 25, j = r - i * 25;
        const float4* q = (const float4*)&qkb[i * 52 + h * 8];
        const float4* kp = (const float4*)&qkb[j * 52 + 24 + h * 8];
        float4 q0 = q[0], q1 = q[1], k0 = kp[0], k1 = kp[1];
        float d = q0.x*k0.x + q0.y*k0.y + q0.z*k0.z + q0.w*k0.w
                + q1.x*k1.x + q1.y*k1.y + q1.z*k1.z + q1.w*k1.w;
        Abuf[idx] = d * 0.35355339059327373f;
    }
    __syncthreads();

    // ---- P4: softmax*PA (tid<75, tree-reassociated) -> A_bf ----
    if (tid < 75) {
        int h = tid / 25, i = tid - h * 25;
        const float* row = &Abuf[tid * 25];
        const float* pa = &PA[h * 625 + i * 25];
        float r[25];
        #pragma unroll
        for (int j = 0; j < 25; ++j) r[j] = row[j];
        float m0 = r[0], m1 = r[1], m2 = r[2], m3 = r[3];
        #pragma unroll
        for (int j = 4; j < 24; j += 4) {
            m0 = fmaxf(m0, r[j]);   m1 = fmaxf(m1, r[j+1]);
            m2 = fmaxf(m2, r[j+2]); m3 = fmaxf(m3, r[j+3]);
        }
        float m = fmaxf(fmaxf(fmaxf(m0, m1), fmaxf(m2, m3)), r[24]);
        float e[25];
        float s0 = 0.f, s1 = 0.f, s2 = 0.f, s3 = 0.f;
        #pragma unroll
        for (int j = 0; j < 24; j += 4) {
            e[j]   = __expf(r[j]   - m); s0 += e[j];
            e[j+1] = __expf(r[j+1] - m); s1 += e[j+1];
            e[j+2] = __expf(r[j+2] - m); s2 += e[j+2];
            e[j+3] = __expf(r[j+3] - m); s3 += e[j+3];
        }
        e[24] = __expf(r[24] - m);
        float inv = 1.0f / (((s0 + s1) + (s2 + s3)) + e[24]);
        unsigned short* ar = &A_bf[tid * 36];
        #pragma unroll
        for (int j = 0; j < 25; ++j) ar[j] = f2bf(e[j] * inv * pa[j]);
        #pragma unroll
        for (int j = 25; j < 32; ++j) ar[j] = 0;
    }
    __syncthreads();

    // ---- P5: out = sum_h A_h . U_h  + BN + residual + ReLU -> res ----
    {
        bf16x8 bF[3];
        #pragma unroll
        for (int h = 0; h < 3; ++h)
            bF[h] = *(bf16x8*)&U_T[(h * 64 + o) * 36 + 8 * g];
        f32x4 acc0 = {0.f, 0.f, 0.f, 0.f}, acc1 = {0.f, 0.f, 0.f, 0.f};
        #pragma unroll
        for (int h = 0; h < 3; ++h) {
            bf16x8 a0 = *(bf16x8*)&A_bf[(h * 25 + l15) * 36 + 8 * g];
            bf16x8 a1 = *(bf16x8*)&A_bf[(h * 25 + 16 + l15) * 36 + 8 * g];
            acc0 = __builtin_amdgcn_mfma_f32_16x16x32_bf16(a0, bF[h], acc0, 0, 0, 0);
            acc1 = __builtin_amdgcn_mfma_f32_16x16x32_bf16(a1, bF[h], acc1, 0, 0, 0);
        }
        #pragma unroll
        for (int reg = 0; reg < 4; ++reg) {
            int v = 4 * g + reg;
            float val = acc0[reg] * sc_e + bi_e + xv[v * 65 + o];
            res[o * 25 + v] = fmaxf(val, 0.f);
        }
        #pragma unroll
        for (int reg = 0; reg < 4; ++reg) {
            int v = 16 + 4 * g + reg;
            if (v < 25) {
                float val = acc1[reg] * sc_e + bi_e + xv[v * 65 + o];
                res[o * 25 + v] = fmaxf(val, 0.f);
            }
        }
    }
    __syncthreads();

    // ---- coalesced store ----
    {
        float* ob = out + (size_t)n * 204800 + t * 25;
        for (int idx = tid; idx < 1600; idx += 256) {
            int c = idx / 25, v = idx - c * 25;
            ob[c * 3200 + v] = res[idx];
        }
    }
}

extern "C" void kernel_launch(void* const* d_in, const int* in_sizes, int n_in,
                              void* d_out, int out_size, void* d_ws, size_t ws_size,
                              hipStream_t stream) {
    const float* x      = (const float*)d_in[0];
    const float* PA     = (const float*)d_in[1];
    const float* ln_g   = (const float*)d_in[2];
    const float* ln_b   = (const float*)d_in[3];
    const float* Wqk    = (const float*)d_in[4];
    const float* bqk    = (const float*)d_in[5];
    const float* conv_w = (const float*)d_in[6];
    const float* conv_b = (const float*)d_in[7];
    const float* bn_g   = (const float*)d_in[8];
    const float* bn_b   = (const float*)d_in[9];
    const float* bn_m   = (const float*)d_in[10];
    const float* bn_v   = (const float*)d_in[11];
    float* outp = (float*)d_out;

    agcn_fused_kernel<<<dim3(128 * 128), dim3(256), 0, stream>>>(
        x, PA, ln_g, ln_b, Wqk, bqk, conv_w, conv_b,
        bn_g, bn_b, bn_m, bn_v, outp);
}

// Round 10
// 324.599 us; speedup vs baseline: 1.4352x; 1.4352x over previous
//
#include <hip/hip_runtime.h>
#include <hip/hip_bf16.h>
#include <math.h>

typedef __attribute__((ext_vector_type(8))) short bf16x8;
typedef __attribute__((ext_vector_type(4))) float f32x4;

__device__ inline unsigned short f2bf(float f) {
    return __builtin_bit_cast(unsigned short, __float2bfloat16(f));
}
__device__ inline float bf2f(unsigned short u) {
    return __bfloat162float(__builtin_bit_cast(__hip_bfloat16, u));
}
__device__ inline bf16x8 cvt8(float4 a, float4 b) {
    bf16x8 r;
    r[0]=(short)f2bf(a.x); r[1]=(short)f2bf(a.y); r[2]=(short)f2bf(a.z); r[3]=(short)f2bf(a.w);
    r[4]=(short)f2bf(b.x); r[5]=(short)f2bf(b.y); r[6]=(short)f2bf(b.z); r[7]=(short)f2bf(b.w);
    return r;
}
__device__ inline void split8(float4 a, float4 b, bf16x8& hi, bf16x8& lo) {
    float f[8] = {a.x,a.y,a.z,a.w,b.x,b.y,b.z,b.w};
    #pragma unroll
    for (int i = 0; i < 8; ++i) {
        unsigned short h = f2bf(f[i]);
        hi[i] = (short)h;
        lo[i] = (short)f2bf(f[i] - bf2f(h));
    }
}

// LDS map (float-index units; total 8003 fl = 32012 B -> 5 blocks/CU):
//  xv   f32 [25][65]     @0          whole block
//  ynh  u16 [25][64]swz  @1628       P1->P2 (spill rows>=25 read ynl: garbage, discarded)
//  ynl  u16 [25][64]swz  @2428       P1->P2 (spill into qkb: garbage, discarded)
//  xvT  u16 [64][40]     @1628       P4->P5 (overlays dead ynh + ynl head)
//  qkb  f32 [25][52]     @3228       P2->P3
//  zA   u16 [25][200]    @2908       P5->P6 (over dead ynl-tail/qkb/Abuf-head; disjoint xvT,A_bf)
//  Abuf f32 [75][25]     @4528       P3->P4
//  res  f32 [64][25]     @5408       P6->P7 (over dead Abuf-tail + dead A_bf head)
//  A_bf u16 [80][40]     @6403       P4->P5
#define LDS_FLOATS 8003

__global__ __launch_bounds__(256, 5)
void agcn_fused_kernel(const float* __restrict__ x,
                       const float* __restrict__ PA,
                       const float* __restrict__ ln_g, const float* __restrict__ ln_b,
                       const float* __restrict__ Wqk, const float* __restrict__ bqk,
                       const float* __restrict__ conv_w, const float* __restrict__ conv_b,
                       const float* __restrict__ bn_g, const float* __restrict__ bn_b,
                       const float* __restrict__ bn_m, const float* __restrict__ bn_v,
                       float* __restrict__ out)
{
    __shared__ float lds[LDS_FLOATS];
    float* xv = lds;                                      // [25][65]
    unsigned short* ynh  = (unsigned short*)(lds + 1628);
    unsigned short* ynl  = (unsigned short*)(lds + 2428);
    unsigned short* xvT  = (unsigned short*)(lds + 1628); // [64][40]
    float* qkb  = lds + 3228;                             // [25][52]
    unsigned short* zA   = (unsigned short*)(lds + 2908); // [25][200]
    float* Abuf = lds + 4528;                             // [75][25]
    float* res  = lds + 5408;                             // [64][25]
    unsigned short* A_bf = (unsigned short*)(lds + 6403); // [80][40]

    const int bid = blockIdx.x;
    const int n = bid >> 7, t = bid & 127;
    const int tid = threadIdx.x;
    const int lane = tid & 63, w = tid >> 6;
    const int g = lane >> 4, l15 = lane & 15;
    const int o = 16 * w + l15;

    // ============ prologue: issue all param loads ============
    float4 cw_f[12];
    #pragma unroll
    for (int kt = 0; kt < 6; ++kt) {
        const float* wp = &conv_w[(kt >> 1) * 4096 + o * 64 + (kt & 1) * 32 + 8 * g];
        cw_f[2*kt]   = *(const float4*)wp;
        cw_f[2*kt+1] = *(const float4*)(wp + 4);
    }
    float4 wq_f[4];
    float bq = 0.f;
    if (w < 3) {
        const int j = 16 * w + l15;
        #pragma unroll
        for (int ks = 0; ks < 2; ++ks) {
            const float* wp = &Wqk[j * 64 + ks * 32 + 8 * g];
            wq_f[2*ks]   = *(const float4*)wp;
            wq_f[2*ks+1] = *(const float4*)(wp + 4);
        }
        bq = bqk[j];
    }
    const float lg = ln_g[lane], lb = ln_b[lane];
    const float sc_e = bn_g[o] * rsqrtf(bn_v[o] + 1e-5f);
    const float bi_e = (conv_b[o] + conv_b[64 + o] + conv_b[128 + o]) * sc_e
                       + bn_b[o] - bn_m[o] * sc_e;

    // ---- P0: stage x tile ----
    {
        const float* xb = x + (size_t)n * 204800 + t * 25;
        for (int idx = tid; idx < 1600; idx += 256) {
            int c = idx / 25, v = idx - c * 25;
            xv[v * 65 + c] = xb[c * 3200 + v];
        }
    }

    bf16x8 cw[6];
    #pragma unroll
    for (int kt = 0; kt < 6; ++kt) cw[kt] = cvt8(cw_f[2*kt], cw_f[2*kt+1]);
    bf16x8 wqh[2], wql[2];
    if (w < 3) {
        #pragma unroll
        for (int ks = 0; ks < 2; ++ks) split8(wq_f[2*ks], wq_f[2*ks+1], wqh[ks], wql[ks]);
    }
    __syncthreads();

    // ---- P1: LayerNorm -> ynh/ynl (bf16 hi/lo, swizzled) ----
    for (int v = w; v < 25; v += 4) {
        float val = xv[v * 65 + lane];
        float s1 = val;
        for (int off = 32; off; off >>= 1) s1 += __shfl_xor(s1, off);
        float mu = s1 * (1.0f / 64.0f);
        float d = val - mu;
        float s2 = d * d;
        for (int off = 32; off; off >>= 1) s2 += __shfl_xor(s2, off);
        float rstd = rsqrtf(s2 * (1.0f / 64.0f) + 1e-5f);
        float y = d * rstd * lg + lb;
        unsigned short hh = f2bf(y);
        unsigned short ll = f2bf(y - bf2f(hh));
        int idx = (v * 64 + lane) ^ ((v & 7) << 3);
        ynh[idx] = hh;
        ynl[idx] = ll;
    }
    __syncthreads();

    // ---- P2: qk MFMA (waves 0-2) -> qkb f32 ----
    if (w < 3) {
        const int j = 16 * w + l15;
        #pragma unroll
        for (int mt = 0; mt < 2; ++mt) {
            f32x4 acc = {bq, bq, bq, bq};
            #pragma unroll
            for (int ks = 0; ks < 2; ++ks) {
                int row = 16 * mt + l15;
                int idx = (row * 64 + ks * 32 + 8 * g) ^ ((row & 7) << 3);
                bf16x8 ah = *(bf16x8*)&ynh[idx];
                bf16x8 al = *(bf16x8*)&ynl[idx];
                acc = __builtin_amdgcn_mfma_f32_16x16x32_bf16(al, wqh[ks], acc, 0, 0, 0);
                acc = __builtin_amdgcn_mfma_f32_16x16x32_bf16(ah, wql[ks], acc, 0, 0, 0);
                acc = __builtin_amdgcn_mfma_f32_16x16x32_bf16(ah, wqh[ks], acc, 0, 0, 0);
            }
            #pragma unroll
            for (int reg = 0; reg < 4; ++reg) {
                int v = 16 * mt + 4 * g + reg;
                if (v < 25) qkb[v * 52 + j] = acc[reg];
            }
        }
    }
    __syncthreads();

    // ---- P3: dots, row-per-thread (q loaded once) -> Abuf ----
    if (tid < 225) {
        int grp = tid / 75;               // 0,1,2 -> j-range
        int r = tid - grp * 75;           // (h,i) row
        int h = (r < 25) ? 0 : ((r < 50) ? 1 : 2);
        int i = r - h * 25;
        const float4* q = (const float4*)&qkb[i * 52 + h * 8];
        float4 q0 = q[0], q1 = q[1];
        int j0 = grp * 8;
        int jend = (grp == 2) ? 25 : (j0 + 8);
        for (int j = j0; j < jend; ++j) {
            const float4* kp = (const float4*)&qkb[j * 52 + 24 + h * 8];
            float4 k0 = kp[0], k1 = kp[1];
            float d = q0.x*k0.x + q0.y*k0.y + q0.z*k0.z + q0.w*k0.w
                    + q1.x*k1.x + q1.y*k1.y + q1.z*k1.z + q1.w*k1.w;
            Abuf[r * 25 + j] = d * 0.35355339059327373f;
        }
    }
    __syncthreads();

    // ---- P4: softmax*PA (tid<75) -> A_bf ; xvT build (tid>=96) ----
    if (tid < 75) {
        int h = (tid < 25) ? 0 : ((tid < 50) ? 1 : 2);
        int i = tid - h * 25;
        const float* row = &Abuf[tid * 25];
        const float* pa = &PA[h * 625 + i * 25];
        float rr[25];
        #pragma unroll
        for (int j = 0; j < 25; ++j) rr[j] = row[j];
        float m0 = rr[0], m1 = rr[1], m2 = rr[2], m3 = rr[3];
        #pragma unroll
        for (int j = 4; j < 24; j += 4) {
            m0 = fmaxf(m0, rr[j]);   m1 = fmaxf(m1, rr[j+1]);
            m2 = fmaxf(m2, rr[j+2]); m3 = fmaxf(m3, rr[j+3]);
        }
        float m = fmaxf(fmaxf(fmaxf(m0, m1), fmaxf(m2, m3)), rr[24]);
        float e[25];
        float s0 = 0.f, s1 = 0.f, s2 = 0.f, s3 = 0.f;
        #pragma unroll
        for (int j = 0; j < 24; j += 4) {
            e[j]   = __expf(rr[j]   - m); s0 += e[j];
            e[j+1] = __expf(rr[j+1] - m); s1 += e[j+1];
            e[j+2] = __expf(rr[j+2] - m); s2 += e[j+2];
            e[j+3] = __expf(rr[j+3] - m); s3 += e[j+3];
        }
        e[24] = __expf(rr[24] - m);
        float inv = 1.0f / (((s0 + s1) + (s2 + s3)) + e[24]);
        unsigned short* ar = &A_bf[tid * 40];
        #pragma unroll
        for (int j = 0; j < 25; ++j) ar[j] = f2bf(e[j] * inv * pa[j]);
        #pragma unroll
        for (int j = 25; j < 32; ++j) ar[j] = 0;
    } else if (tid >= 96) {
        for (int idx = tid - 96; idx < 2560; idx += 160) {
            int c = idx / 40, jj = idx - c * 40;
            xvT[idx] = f2bf(jj < 25 ? xv[jj * 65 + c] : 0.f);
        }
    }
    __syncthreads();

    // ---- P5: z MFMA + direct zA write (dedicated region, no defer) ----
    {
        bf16x8 bfrag = *(bf16x8*)&xvT[(16 * w + l15) * 40 + 8 * g];
        #pragma unroll
        for (int mt = 0; mt < 5; ++mt) {
            bf16x8 afrag = *(bf16x8*)&A_bf[(16 * mt + l15) * 40 + 8 * g];
            f32x4 a = {0.f, 0.f, 0.f, 0.f};
            a = __builtin_amdgcn_mfma_f32_16x16x32_bf16(afrag, bfrag, a, 0, 0, 0);
            #pragma unroll
            for (int reg = 0; reg < 4; ++reg) {
                int r = 16 * mt + 4 * g + reg;
                if (r < 75) {
                    int h = (r < 25) ? 0 : ((r < 50) ? 1 : 2);
                    int i = r - h * 25;
                    zA[i * 200 + h * 64 + 16 * w + l15] = f2bf(a[reg]);
                }
            }
        }
    }
    __syncthreads();

    // ---- P6: conv MFMA + BN + residual + ReLU -> res ----
    {
        const int r1 = (16 + l15 < 25) ? (16 + l15) : 0;
        f32x4 acc0 = {0.f, 0.f, 0.f, 0.f}, acc1 = {0.f, 0.f, 0.f, 0.f};
        #pragma unroll
        for (int kt = 0; kt < 6; ++kt) {
            bf16x8 a0 = *(bf16x8*)&zA[l15 * 200 + 32 * kt + 8 * g];
            bf16x8 a1 = *(bf16x8*)&zA[r1 * 200 + 32 * kt + 8 * g];
            acc0 = __builtin_amdgcn_mfma_f32_16x16x32_bf16(a0, cw[kt], acc0, 0, 0, 0);
            acc1 = __builtin_amdgcn_mfma_f32_16x16x32_bf16(a1, cw[kt], acc1, 0, 0, 0);
        }
        #pragma unroll
        for (int reg = 0; reg < 4; ++reg) {
            int v = 4 * g + reg;
            float val = acc0[reg] * sc_e + bi_e + xv[v * 65 + o];
            res[o * 25 + v] = fmaxf(val, 0.f);
        }
        #pragma unroll
        for (int reg = 0; reg < 4; ++reg) {
            int v = 16 + 4 * g + reg;
            if (v < 25) {
                float val = acc1[reg] * sc_e + bi_e + xv[v * 65 + o];
                res[o * 25 + v] = fmaxf(val, 0.f);
            }
        }
    }
    __syncthreads();

    // ---- P7: coalesced store ----
    {
        float* ob = out + (size_t)n * 204800 + t * 25;
        for (int idx = tid; idx < 1600; idx += 256) {
            int c = idx / 25, v = idx - c * 25;
            ob[c * 3200 + v] = res[idx];
        }
    }
}

extern "C" void kernel_launch(void* const* d_in, const int* in_sizes, int n_in,
                              void* d_out, int out_size, void* d_ws, size_t ws_size,
                              hipStream_t stream) {
    const float* x      = (const float*)d_in[0];
    const float* PA     = (const float*)d_in[1];
    const float* ln_g   = (const float*)d_in[2];
    const float* ln_b   = (const float*)d_in[3];
    const float* Wqk    = (const float*)d_in[4];
    const float* bqk    = (const float*)d_in[5];
    const float* conv_w = (const float*)d_in[6];
    const float* conv_b = (const float*)d_in[7];
    const float* bn_g   = (const float*)d_in[8];
    const float* bn_b   = (const float*)d_in[9];
    const float* bn_m   = (const float*)d_in[10];
    const float* bn_v   = (const float*)d_in[11];
    float* outp = (float*)d_out;

    agcn_fused_kernel<<<dim3(128 * 128), dim3(256), 0, stream>>>(
        x, PA, ln_g, ln_b, Wqk, bqk, conv_w, conv_b,
        bn_g, bn_b, bn_m, bn_v, outp);
}

// Round 11
// 270.773 us; speedup vs baseline: 1.7205x; 1.1988x over previous
//
#include <hip/hip_runtime.h>
#include <hip/hip_bf16.h>
#include <math.h>

typedef __attribute__((ext_vector_type(8))) short bf16x8;
typedef __attribute__((ext_vector_type(4))) float f32x4;

__device__ inline unsigned short f2bf(float f) {
    return __builtin_bit_cast(unsigned short, __float2bfloat16(f));
}
__device__ inline float bf2f(unsigned short u) {
    return __bfloat162float(__builtin_bit_cast(__hip_bfloat16, u));
}
__device__ inline bf16x8 cvt8(float4 a, float4 b) {
    bf16x8 r;
    r[0]=(short)f2bf(a.x); r[1]=(short)f2bf(a.y); r[2]=(short)f2bf(a.z); r[3]=(short)f2bf(a.w);
    r[4]=(short)f2bf(b.x); r[5]=(short)f2bf(b.y); r[6]=(short)f2bf(b.z); r[7]=(short)f2bf(b.w);
    return r;
}
__device__ inline void split8(float4 a, float4 b, bf16x8& hi, bf16x8& lo) {
    float f[8] = {a.x,a.y,a.z,a.w,b.x,b.y,b.z,b.w};
    #pragma unroll
    for (int i = 0; i < 8; ++i) {
        unsigned short h = f2bf(f[i]);
        hi[i] = (short)h;
        lo[i] = (short)f2bf(f[i] - bf2f(h));
    }
}

// LDS map (float-index units; total 7755 fl = 31020 B -> 5 blocks/CU):
//  xv   f32 [25][68]     @0     P0->end (LN src b128-aligned, xvT src, residual)
//  ynh  u16 [25][64]swz  @1700  P1->P2 (rows 25-31 spill-read into ynl: garbage, discarded)
//  ynl  u16 [25][64]swz  @2500  P1->P2 (spill-read into qkb: garbage, discarded)
//  qkb  f32 [25][52]     @3300  P2->P3
//  xvT  u16 [64][40]     @4600  P1->P5 (dedicated; built in P1)
//  Abuf f32 [75][25]     @5880  P3->P4
//  A_bf u16 [80][40]     @1700  P4->P5 (over dead yn; rows 75-79 spill stay < @3300)
//  zA   u16 [25][200]    @1700  after P5-drain -> P6 (over dead A_bf/qkb; ends @4200)
//  res  f32 [64][25]     @5880  P6->store (over dead Abuf)
#define LDS_FLOATS 7755

__global__ __launch_bounds__(256, 5)
void agcn_fused_kernel(const float* __restrict__ x,
                       const float* __restrict__ PA,
                       const float* __restrict__ ln_g, const float* __restrict__ ln_b,
                       const float* __restrict__ Wqk, const float* __restrict__ bqk,
                       const float* __restrict__ conv_w, const float* __restrict__ conv_b,
                       const float* __restrict__ bn_g, const float* __restrict__ bn_b,
                       const float* __restrict__ bn_m, const float* __restrict__ bn_v,
                       float* __restrict__ out)
{
    __shared__ float lds[LDS_FLOATS];
    float* xv = lds;                                      // [25][68]
    unsigned short* ynh  = (unsigned short*)(lds + 1700);
    unsigned short* ynl  = (unsigned short*)(lds + 2500);
    float* qkb  = lds + 3300;                             // [25][52]
    unsigned short* xvT  = (unsigned short*)(lds + 4600); // [64][40]
    float* Abuf = lds + 5880;                             // [75][25]
    unsigned short* A_bf = (unsigned short*)(lds + 1700); // [80][40]
    unsigned short* zA   = (unsigned short*)(lds + 1700); // [25][200]
    float* res  = lds + 5880;                             // [64][25]

    const int bid = blockIdx.x;
    const int n = bid >> 7, t = bid & 127;
    const int tid = threadIdx.x;
    const int lane = tid & 63, w = tid >> 6;
    const int g = lane >> 4, l15 = lane & 15;
    const int o = 16 * w + l15;

    // ============ prologue: issue all param loads ============
    float4 cw_f[12];
    #pragma unroll
    for (int kt = 0; kt < 6; ++kt) {
        const float* wp = &conv_w[(kt >> 1) * 4096 + o * 64 + (kt & 1) * 32 + 8 * g];
        cw_f[2*kt]   = *(const float4*)wp;
        cw_f[2*kt+1] = *(const float4*)(wp + 4);
    }
    float4 wq_f[4];
    float bq = 0.f;
    if (w < 3) {
        const int j = 16 * w + l15;
        #pragma unroll
        for (int ks = 0; ks < 2; ++ks) {
            const float* wp = &Wqk[j * 64 + ks * 32 + 8 * g];
            wq_f[2*ks]   = *(const float4*)wp;
            wq_f[2*ks+1] = *(const float4*)(wp + 4);
        }
        bq = bqk[j];
    }
    // per-lane LN params for the 8 columns this lane owns in P1
    const int c0 = (lane & 7) << 3;
    const float4 lg0 = *(const float4*)&ln_g[c0];
    const float4 lg1 = *(const float4*)&ln_g[c0 + 4];
    const float4 lb0 = *(const float4*)&ln_b[c0];
    const float4 lb1 = *(const float4*)&ln_b[c0 + 4];
    const float sc_e = bn_g[o] * rsqrtf(bn_v[o] + 1e-5f);
    const float bi_e = (conv_b[o] + conv_b[64 + o] + conv_b[128 + o]) * sc_e
                       + bn_b[o] - bn_m[o] * sc_e;

    // ---- P0: stage x tile ----
    {
        const float* xb = x + (size_t)n * 204800 + t * 25;
        for (int idx = tid; idx < 1600; idx += 256) {
            int c = idx / 25, v = idx - c * 25;
            xv[v * 68 + c] = xb[c * 3200 + v];
        }
    }

    bf16x8 cw[6];
    #pragma unroll
    for (int kt = 0; kt < 6; ++kt) cw[kt] = cvt8(cw_f[2*kt], cw_f[2*kt+1]);
    bf16x8 wqh[2], wql[2];
    if (w < 3) {
        #pragma unroll
        for (int ks = 0; ks < 2; ++ks) split8(wq_f[2*ks], wq_f[2*ks+1], wqh[ks], wql[ks]);
    }
    __syncthreads();

    // ---- P1: one-pass LN (8-lane group per row, all rows parallel) + xvT build ----
    {
        const int v = (w << 3) + (lane >> 3);
        if (v < 25) {
            const float4* xp = (const float4*)&xv[v * 68 + c0];
            float4 a = xp[0], b = xp[1];
            float s1 = ((a.x + a.y) + (a.z + a.w)) + ((b.x + b.y) + (b.z + b.w));
            float s2 = ((a.x*a.x + a.y*a.y) + (a.z*a.z + a.w*a.w))
                     + ((b.x*b.x + b.y*b.y) + (b.z*b.z + b.w*b.w));
            s1 += __shfl_xor(s1, 1);  s2 += __shfl_xor(s2, 1);
            s1 += __shfl_xor(s1, 2);  s2 += __shfl_xor(s2, 2);
            s1 += __shfl_xor(s1, 4);  s2 += __shfl_xor(s2, 4);
            float mu = s1 * (1.0f / 64.0f);
            float var = s2 * (1.0f / 64.0f) - mu * mu;
            float rstd = rsqrtf(var + 1e-5f);
            float xa[8] = {a.x,a.y,a.z,a.w,b.x,b.y,b.z,b.w};
            float lg[8] = {lg0.x,lg0.y,lg0.z,lg0.w,lg1.x,lg1.y,lg1.z,lg1.w};
            float lb[8] = {lb0.x,lb0.y,lb0.z,lb0.w,lb1.x,lb1.y,lb1.z,lb1.w};
            bf16x8 hh8, ll8;
            #pragma unroll
            for (int i = 0; i < 8; ++i) {
                float y = (xa[i] - mu) * rstd * lg[i] + lb[i];
                unsigned short hh = f2bf(y);
                hh8[i] = (short)hh;
                ll8[i] = (short)f2bf(y - bf2f(hh));
            }
            int base = (v * 64 + c0) ^ ((v & 7) << 3);
            *(bf16x8*)&ynh[base] = hh8;
            *(bf16x8*)&ynl[base] = ll8;
        }
        // xvT: one b128 task per thread: row c = tid>>2, j-chunk j0 = (tid&3)*8
        int c = tid >> 2, j0 = (tid & 3) << 3;
        bf16x8 pk;
        #pragma unroll
        for (int i = 0; i < 8; ++i) {
            int j = j0 + i;
            pk[i] = (j < 25) ? (short)f2bf(xv[j * 68 + c]) : (short)0;
        }
        *(bf16x8*)&xvT[c * 40 + j0] = pk;
    }
    __syncthreads();

    // ---- P2: qk MFMA (waves 0-2) -> qkb f32 ----
    if (w < 3) {
        const int j = 16 * w + l15;
        #pragma unroll
        for (int mt = 0; mt < 2; ++mt) {
            f32x4 acc = {bq, bq, bq, bq};
            #pragma unroll
            for (int ks = 0; ks < 2; ++ks) {
                int row = 16 * mt + l15;
                int idx = (row * 64 + ks * 32 + 8 * g) ^ ((row & 7) << 3);
                bf16x8 ah = *(bf16x8*)&ynh[idx];
                bf16x8 al = *(bf16x8*)&ynl[idx];
                acc = __builtin_amdgcn_mfma_f32_16x16x32_bf16(al, wqh[ks], acc, 0, 0, 0);
                acc = __builtin_amdgcn_mfma_f32_16x16x32_bf16(ah, wql[ks], acc, 0, 0, 0);
                acc = __builtin_amdgcn_mfma_f32_16x16x32_bf16(ah, wqh[ks], acc, 0, 0, 0);
            }
            #pragma unroll
            for (int reg = 0; reg < 4; ++reg) {
                int v = 16 * mt + 4 * g + reg;
                if (v < 25) qkb[v * 52 + j] = acc[reg];
            }
        }
    }
    __syncthreads();

    // ---- P3: dots (fp32 VALU, all threads) -> Abuf ----
    for (int idx = tid; idx < 1875; idx += 256) {
        int h = idx / 625, r = idx - h * 625;
        int i = r / 25, j = r - i * 25;
        const float4* q = (const float4*)&qkb[i * 52 + h * 8];
        const float4* kp = (const float4*)&qkb[j * 52 + 24 + h * 8];
        float4 q0 = q[0], q1 = q[1], k0 = kp[0], k1 = kp[1];
        float d = q0.x*k0.x + q0.y*k0.y + q0.z*k0.z + q0.w*k0.w
                + q1.x*k1.x + q1.y*k1.y + q1.z*k1.z + q1.w*k1.w;
        Abuf[idx] = d * 0.35355339059327373f;
    }
    __syncthreads();

    // ---- P4: softmax*PA, 2 threads per row -> A_bf ----
    if (tid < 150) {
        int r = tid >> 1, hf = tid & 1;
        int h = (r < 25) ? 0 : ((r < 50) ? 1 : 2);
        int i = r - h * 25;
        int j0 = hf ? 13 : 0;
        const float* row = &Abuf[r * 25];
        const float* pa = &PA[h * 625 + i * 25];
        float rr[13];
        #pragma unroll
        for (int j = 0; j < 13; ++j) {
            int jj = j0 + j;
            rr[j] = (jj < 25) ? row[jj] : -3.0e38f;
        }
        float m0 = fmaxf(rr[0], rr[1]), m1 = fmaxf(rr[2], rr[3]);
        float m2 = fmaxf(rr[4], rr[5]), m3 = fmaxf(rr[6], rr[7]);
        float m4 = fmaxf(rr[8], rr[9]), m5 = fmaxf(rr[10], rr[11]);
        float m = fmaxf(fmaxf(fmaxf(m0, m1), fmaxf(m2, m3)),
                        fmaxf(fmaxf(m4, m5), rr[12]));
        m = fmaxf(m, __shfl_xor(m, 1));
        float e[13];
        float s0 = 0.f, s1 = 0.f;
        #pragma unroll
        for (int j = 0; j < 12; j += 2) {
            e[j]   = __expf(rr[j]   - m); s0 += e[j];
            e[j+1] = __expf(rr[j+1] - m); s1 += e[j+1];
        }
        e[12] = __expf(rr[12] - m);
        float s = (s0 + s1) + e[12];
        s += __shfl_xor(s, 1);
        float inv = 1.0f / s;
        unsigned short* ar = &A_bf[r * 40];
        #pragma unroll
        for (int j = 0; j < 13; ++j) {
            int jj = j0 + j;
            if (jj < 25) ar[jj] = f2bf(e[j] * inv * pa[jj]);
        }
        if (hf) {
            #pragma unroll
            for (int j = 25; j < 32; ++j) ar[j] = 0;
        }
    }
    __syncthreads();

    // ---- P5: z MFMA -> regs (zA write deferred past drain barrier) ----
    f32x4 zacc[5];
    {
        bf16x8 bfrag = *(bf16x8*)&xvT[(16 * w + l15) * 40 + 8 * g];
        #pragma unroll
        for (int mt = 0; mt < 5; ++mt) {
            bf16x8 afrag = *(bf16x8*)&A_bf[(16 * mt + l15) * 40 + 8 * g];
            f32x4 a = {0.f, 0.f, 0.f, 0.f};
            zacc[mt] = __builtin_amdgcn_mfma_f32_16x16x32_bf16(afrag, bfrag, a, 0, 0, 0);
        }
    }
    __syncthreads();   // frag reads drained; A_bf/qkb dead -> zA region free

    #pragma unroll
    for (int mt = 0; mt < 5; ++mt) {
        #pragma unroll
        for (int reg = 0; reg < 4; ++reg) {
            int r = 16 * mt + 4 * g + reg;
            if (r < 75) {
                int h = (r < 25) ? 0 : ((r < 50) ? 1 : 2);
                int i = r - h * 25;
                zA[i * 200 + h * 64 + 16 * w + l15] = f2bf(zacc[mt][reg]);
            }
        }
    }
    __syncthreads();

    // ---- P6: conv MFMA + BN + residual + ReLU -> res ----
    {
        const int r1 = (16 + l15 < 25) ? (16 + l15) : 0;
        f32x4 acc0 = {0.f, 0.f, 0.f, 0.f}, acc1 = {0.f, 0.f, 0.f, 0.f};
        #pragma unroll
        for (int kt = 0; kt < 6; ++kt) {
            bf16x8 a0 = *(bf16x8*)&zA[l15 * 200 + 32 * kt + 8 * g];
            bf16x8 a1 = *(bf16x8*)&zA[r1 * 200 + 32 * kt + 8 * g];
            acc0 = __builtin_amdgcn_mfma_f32_16x16x32_bf16(a0, cw[kt], acc0, 0, 0, 0);
            acc1 = __builtin_amdgcn_mfma_f32_16x16x32_bf16(a1, cw[kt], acc1, 0, 0, 0);
        }
        #pragma unroll
        for (int reg = 0; reg < 4; ++reg) {
            int v = 4 * g + reg;
            float val = acc0[reg] * sc_e + bi_e + xv[v * 68 + o];
            res[o * 25 + v] = fmaxf(val, 0.f);
        }
        #pragma unroll
        for (int reg = 0; reg < 4; ++reg) {
            int v = 16 + 4 * g + reg;
            if (v < 25) {
                float val = acc1[reg] * sc_e + bi_e + xv[v * 68 + o];
                res[o * 25 + v] = fmaxf(val, 0.f);
            }
        }
    }
    __syncthreads();

    // ---- P7: coalesced store ----
    {
        float* ob = out + (size_t)n * 204800 + t * 25;
        for (int idx = tid; idx < 1600; idx += 256) {
            int c = idx / 25, v = idx - c * 25;
            ob[c * 3200 + v] = res[idx];
        }
    }
}

extern "C" void kernel_launch(void* const* d_in, const int* in_sizes, int n_in,
                              void* d_out, int out_size, void* d_ws, size_t ws_size,
                              hipStream_t stream) {
    const float* x      = (const float*)d_in[0];
    const float* PA     = (const float*)d_in[1];
    const float* ln_g   = (const float*)d_in[2];
    const float* ln_b   = (const float*)d_in[3];
    const float* Wqk    = (const float*)d_in[4];
    const float* bqk    = (const float*)d_in[5];
    const float* conv_w = (const float*)d_in[6];
    const float* conv_b = (const float*)d_in[7];
    const float* bn_g   = (const float*)d_in[8];
    const float* bn_b   = (const float*)d_in[9];
    const float* bn_m   = (const float*)d_in[10];
    const float* bn_v   = (const float*)d_in[11];
    float* outp = (float*)d_out;

    agcn_fused_kernel<<<dim3(128 * 128), dim3(256), 0, stream>>>(
        x, PA, ln_g, ln_b, Wqk, bqk, conv_w, conv_b,
        bn_g, bn_b, bn_m, bn_v, outp);
}